// Round 3
// baseline (1109.796 us; speedup 1.0000x reference)
//
#include <hip/hip_runtime.h>
#include <stdint.h>

// ---------------- problem constants ----------------
#define T_TREES 10
#define IN_DIM  2048
#define BATCH   16384
#define CLASSES 1000
#define NDEC    255
#define NPAD    256          // decisions padded to 256
#define K2DIM   (T_TREES * NPAD)  // 2560
#define NPADC   1024         // classes padded to 1024

typedef unsigned short u16;
typedef float floatx4 __attribute__((ext_vector_type(4)));
typedef __bf16 bf16x8 __attribute__((ext_vector_type(8)));

// ---------------- helpers ----------------
__device__ __forceinline__ u16 f2bf(float f) {
    union { float f; uint32_t u; } v; v.f = f;
    uint32_t u = v.u;
    return (u16)((u + 0x7FFFu + ((u >> 16) & 1u)) >> 16);   // RNE
}
__device__ __forceinline__ float bf2f(u16 h) {
    union { uint32_t u; float f; } v; v.u = ((uint32_t)h) << 16;
    return v.f;
}

// async global->LDS, 16B per lane. LDS dest is wave-uniform base; HW writes
// lane i at base + i*16.
__device__ __forceinline__ void gld16(u16* lds, const u16* g) {
    __builtin_amdgcn_global_load_lds(
        (__attribute__((address_space(1))) const void*)g,
        (__attribute__((address_space(3))) void*)lds,
        16, 0, 0);
}

// ---------------- kernel 0: x fp32 -> bf16 ----------------
__global__ __launch_bounds__(256) void cast_x_k(const float4* __restrict__ x,
                                                uint2* __restrict__ xb) {
    int i = blockIdx.x * 256 + threadIdx.x;   // grid sized exactly
    float4 v = x[i];
    uint2 o;
    o.x = (uint32_t)f2bf(v.x) | ((uint32_t)f2bf(v.y) << 16);
    o.y = (uint32_t)f2bf(v.z) | ((uint32_t)f2bf(v.w) << 16);
    xb[i] = o;
}

// ---------------- kernel 1: w_d [t,i,255] fp32 -> wdT [t,256,2048] bf16 ----
__global__ void transpose_wd_k(const float* __restrict__ wd, u16* __restrict__ wdT) {
    __shared__ float tile[32][33];
    int tx = threadIdx.x, ty = threadIdx.y;
    int t = blockIdx.z;
    int i0 = blockIdx.x * 32, d0 = blockIdx.y * 32;
#pragma unroll
    for (int r = 0; r < 4; ++r) {
        int i = i0 + ty + r * 8;
        int d = d0 + tx;
        float v = (d < NDEC) ? wd[((size_t)t * IN_DIM + i) * NDEC + d] : 0.0f;
        tile[ty + r * 8][tx] = v;
    }
    __syncthreads();
#pragma unroll
    for (int r = 0; r < 4; ++r) {
        int dd = d0 + ty + r * 8;
        int ii = i0 + tx;
        wdT[((size_t)t * NPAD + dd) * IN_DIM + ii] = f2bf(tile[tx][ty + r * 8]);
    }
}

// ------- kernel 2: softmax(w_l) rows, fold leaf pairs, *0.1 -> B2 [2560,1024] bf16
__global__ __launch_bounds__(256) void softmax_fold_k(const float* __restrict__ wl,
                                                      u16* __restrict__ B2) {
    int wid = threadIdx.x >> 6, lane = threadIdx.x & 63;
    int idx = blockIdx.x * 4 + wid;          // 0..2559 = t*256 + m
    int t = idx >> 8, m = idx & 255;
    const float* r0 = wl + ((size_t)t * 512 + 2 * m) * CLASSES;
    const float* r1 = r0 + CLASSES;
    float v0[16], v1[16];
    float mx0 = -3.0e38f, mx1 = -3.0e38f;
#pragma unroll
    for (int j = 0; j < 16; ++j) {
        int c = lane + 64 * j;
        float a = (c < CLASSES) ? r0[c] : -3.0e38f;
        float b = (c < CLASSES) ? r1[c] : -3.0e38f;
        v0[j] = a; v1[j] = b;
        mx0 = fmaxf(mx0, a); mx1 = fmaxf(mx1, b);
    }
#pragma unroll
    for (int o = 32; o > 0; o >>= 1) {
        mx0 = fmaxf(mx0, __shfl_xor(mx0, o));
        mx1 = fmaxf(mx1, __shfl_xor(mx1, o));
    }
    float s0 = 0.f, s1 = 0.f;
#pragma unroll
    for (int j = 0; j < 16; ++j) {
        int c = lane + 64 * j;
        float e0 = (c < CLASSES) ? __expf(v0[j] - mx0) : 0.f;
        float e1 = (c < CLASSES) ? __expf(v1[j] - mx1) : 0.f;
        v0[j] = e0; v1[j] = e1; s0 += e0; s1 += e1;
    }
#pragma unroll
    for (int o = 32; o > 0; o >>= 1) { s0 += __shfl_xor(s0, o); s1 += __shfl_xor(s1, o); }
    float i0 = 0.1f / s0, i1 = 0.1f / s1;
#pragma unroll
    for (int j = 0; j < 16; ++j) {
        int c = lane + 64 * j;               // covers 0..1023 exactly
        float v = (c < CLASSES) ? (v0[j] * i0 + v1[j] * i1) : 0.f;
        B2[(size_t)idx * NPADC + c] = f2bf(v);
    }
}

// ---------------- kernel 3: B2 [2560,1024] -> B2t [1024,2560] bf16 ----------
__global__ void transpose_b2_k(const u16* __restrict__ B2, u16* __restrict__ B2t) {
    __shared__ u16 tile[32][33];
    int tx = threadIdx.x, ty = threadIdx.y;
    int k0 = blockIdx.x * 32, c0 = blockIdx.y * 32;
#pragma unroll
    for (int r = 0; r < 4; ++r)
        tile[ty + r * 8][tx] = B2[(size_t)(k0 + ty + r * 8) * NPADC + c0 + tx];
    __syncthreads();
#pragma unroll
    for (int r = 0; r < 4; ++r)
        B2t[(size_t)(c0 + ty + r * 8) * K2DIM + k0 + tx] = tile[tx][ty + r * 8];
}

// ---------------- kernel 4: FUSED GEMM1 + sigmoid + leaf products -----------
// One block = 128 batch rows x ALL 256 decision cols of tree t, via two
// sequential 128-col K-loop passes (same per-iter cost as the old split
// blocks; total block-iters unchanged). Pass 0 sigmoid probs -> LDS stash
// (dec 0..127); pass 1 probs stay in registers. The thread holding C(r,c)
// (c in 128..255) owns level-7 decision dec=c, so it computes leaf pair
// m = 2q, 2q+1 (q = c-127): levels 0..6 from stash (dec<=126), level 7 from
// its own register. Pad col 255 is reassigned to leaf pair (0,1), whose
// level-7 decision is dec 127 (read from stash).
// LDS: As 8K + Bs 8K + stash 128x132 u16 (33.8K, stride 132 so a 4-row quad
// offset = 8 banks -> conflict-free-ish) = 50.2 KB -> 3 blocks/CU.
__global__ __launch_bounds__(256, 3) void gemm1_fused_k(const u16* __restrict__ A,
                                                        const u16* __restrict__ Bw,
                                                        u16* __restrict__ lp) {
    __shared__ __align__(16) u16 As[128 * 32];
    __shared__ __align__(16) u16 Bs[128 * 32];
    __shared__ u16 stash[128 * 132];
    const int tid  = threadIdx.x;
    const int wid  = tid >> 6;
    const int lane = tid & 63;
    const int wr = wid >> 1, wc = wid & 1;
    const int quad = lane >> 4, t16 = lane & 15;

    const size_t m0 = (size_t)blockIdx.x * 128;
    const int t = blockIdx.y;
    const u16* Ag = A + m0 * (size_t)IN_DIM;

    // staging (identical swizzled pattern to round 2): wave wid fills 1KiB
    // chunks {2*wid, 2*wid+1}; lane i -> row ch*16+i/4, global segment
    // (i&3)^((i>>3)&3); LDS slot s^((r>>1)&3).
    const int ch0   = wid * 2;
    const int srow0 = ch0 * 16 + (lane >> 2);
    const int skk   = ((lane & 3) ^ ((lane >> 3) & 3)) * 8;
    const u16* ag0 = Ag + (size_t)srow0 * IN_DIM + skk;
    const u16* ag1 = ag0 + (size_t)16 * IN_DIM;
    u16* lA0 = &As[ch0 * 512];
    u16* lA1 = &As[ch0 * 512 + 512];
    u16* lB0 = &Bs[ch0 * 512];
    u16* lB1 = &Bs[ch0 * 512 + 512];
    const int sw = (quad ^ ((t16 >> 1) & 3)) * 8;   // read-side swizzled slot

#pragma unroll 1
    for (int nh = 0; nh < 2; ++nh) {
        const u16* Bg  = Bw + ((size_t)t * NPAD + nh * 128) * (size_t)IN_DIM;
        const u16* bg0 = Bg + (size_t)srow0 * IN_DIM + skk;
        const u16* bg1 = bg0 + (size_t)16 * IN_DIM;

        floatx4 acc[4][4];
#pragma unroll
        for (int i = 0; i < 4; ++i)
#pragma unroll
            for (int j = 0; j < 4; ++j) acc[i][j] = (floatx4){0.f, 0.f, 0.f, 0.f};

        for (int k0 = 0; k0 < IN_DIM; k0 += 32) {
            gld16(lA0, ag0 + k0);
            gld16(lA1, ag1 + k0);
            gld16(lB0, bg0 + k0);
            gld16(lB1, bg1 + k0);
            __syncthreads();   // drains vmcnt for the global_load_lds

            bf16x8 af[4], bfr[4];
#pragma unroll
            for (int mi = 0; mi < 4; ++mi)
                af[mi] = *(const bf16x8*)&As[(wr * 64 + mi * 16 + t16) * 32 + sw];
#pragma unroll
            for (int ni = 0; ni < 4; ++ni)
                bfr[ni] = *(const bf16x8*)&Bs[(wc * 64 + ni * 16 + t16) * 32 + sw];
#pragma unroll
            for (int mi = 0; mi < 4; ++mi)
#pragma unroll
                for (int ni = 0; ni < 4; ++ni)
                    acc[mi][ni] = __builtin_amdgcn_mfma_f32_16x16x32_bf16(
                        af[mi], bfr[ni], acc[mi][ni], 0, 0, 0);
            __syncthreads();   // protect LDS before next stage
        }

        if (nh == 0) {
            // sigmoid -> stash[r][c], c = dec 0..127
#pragma unroll
            for (int mi = 0; mi < 4; ++mi)
#pragma unroll
                for (int r = 0; r < 4; ++r) {
                    int row = wr * 64 + mi * 16 + quad * 4 + r;
#pragma unroll
                    for (int ni = 0; ni < 4; ++ni) {
                        int c = wc * 64 + ni * 16 + t16;
                        float p = 1.0f / (1.0f + __expf(-acc[mi][ni][r]));
                        stash[row * 132 + c] = f2bf(p);
                    }
                }
            // stash-write visibility to other waves is guaranteed by the
            // barriers inside pass 1's K-loop before any epilogue read.
        } else {
            __syncthreads();   // all stash writes + pass-1 accs final
#pragma unroll
            for (int mi = 0; mi < 4; ++mi)
#pragma unroll
                for (int r = 0; r < 4; ++r) {
                    int row = wr * 64 + mi * 16 + quad * 4 + r;
                    size_t grow = m0 + row;
#pragma unroll
                    for (int ni = 0; ni < 4; ++ni) {
                        int c_local = wc * 64 + ni * 16 + t16;   // 0..127
                        int q = (c_local == 127) ? 0 : (c_local + 1);
                        float p = 1.0f / (1.0f + __expf(-acc[mi][ni][r]));
                        if (q == 0) p = bf2f(stash[row * 132 + 127]);
                        float pre = 1.0f;
#pragma unroll
                        for (int n = 0; n < 7; ++n) {
                            int dec  = (1 << n) - 1 + (q >> (7 - n));
                            int side = (q >> (6 - n)) & 1;
                            float f  = bf2f(stash[row * 132 + dec]);
                            pre *= side ? (1.0f - f) : f;
                        }
                        u16 lo = f2bf(pre * p);
                        u16 hi = f2bf(pre * (1.0f - p));
                        *(uint32_t*)&lp[grow * K2DIM + (size_t)t * NPAD + 2 * q] =
                            (uint32_t)lo | ((uint32_t)hi << 16);
                    }
                }
        }
    }
}

// ---------------- kernel 5: GEMM2, 2-step K-unroll (BK=64) ------------------
// C[16384,1000] fp32 = lp[16384,2560] @ B2t[1024,2560]^T. Two LDS buffer
// sets staged before one barrier -> 32 MFMA per barrier, 40 barriers
// (vs 80). LDS 32 KB; MINW=4 -> 4 blocks/CU -> whole 1024-block grid in one
// round. Frag regs reused set0->set1 to stay under the 64-VGPR budget.
__global__ __launch_bounds__(256, 4) void gemm2_k(const u16* __restrict__ A,
                                                  const u16* __restrict__ B,
                                                  float* __restrict__ C) {
    __shared__ __align__(16) u16 As0[128 * 32];
    __shared__ __align__(16) u16 Bs0[128 * 32];
    __shared__ __align__(16) u16 As1[128 * 32];
    __shared__ __align__(16) u16 Bs1[128 * 32];
    const int tid  = threadIdx.x;
    const int wid  = tid >> 6;
    const int lane = tid & 63;
    const int wr = wid >> 1, wc = wid & 1;
    const int quad = lane >> 4, t16 = lane & 15;

    const size_t m0 = (size_t)blockIdx.x * 128;
    const size_t n0 = (size_t)blockIdx.y * 128;
    const u16* Ag = A + m0 * (size_t)K2DIM;
    const u16* Bg = B + n0 * (size_t)K2DIM;

    const int ch0   = wid * 2;
    const int srow0 = ch0 * 16 + (lane >> 2);
    const int skk   = ((lane & 3) ^ ((lane >> 3) & 3)) * 8;
    const u16* ag0 = Ag + (size_t)srow0 * K2DIM + skk;
    const u16* ag1 = ag0 + (size_t)16 * K2DIM;
    const u16* bg0 = Bg + (size_t)srow0 * K2DIM + skk;
    const u16* bg1 = bg0 + (size_t)16 * K2DIM;
    const int co = ch0 * 512;
    const int sw = (quad ^ ((t16 >> 1) & 3)) * 8;

    floatx4 acc[4][4];
#pragma unroll
    for (int i = 0; i < 4; ++i)
#pragma unroll
        for (int j = 0; j < 4; ++j) acc[i][j] = (floatx4){0.f, 0.f, 0.f, 0.f};

    for (int k0 = 0; k0 < K2DIM; k0 += 64) {
        gld16(&As0[co], ag0 + k0);
        gld16(&As0[co + 512], ag1 + k0);
        gld16(&Bs0[co], bg0 + k0);
        gld16(&Bs0[co + 512], bg1 + k0);
        gld16(&As1[co], ag0 + k0 + 32);
        gld16(&As1[co + 512], ag1 + k0 + 32);
        gld16(&Bs1[co], bg0 + k0 + 32);
        gld16(&Bs1[co + 512], bg1 + k0 + 32);
        __syncthreads();   // one drain for both k-steps

        {
            bf16x8 af[4], bfr[4];
#pragma unroll
            for (int mi = 0; mi < 4; ++mi)
                af[mi] = *(const bf16x8*)&As0[(wr * 64 + mi * 16 + t16) * 32 + sw];
#pragma unroll
            for (int ni = 0; ni < 4; ++ni)
                bfr[ni] = *(const bf16x8*)&Bs0[(wc * 64 + ni * 16 + t16) * 32 + sw];
#pragma unroll
            for (int mi = 0; mi < 4; ++mi)
#pragma unroll
                for (int ni = 0; ni < 4; ++ni)
                    acc[mi][ni] = __builtin_amdgcn_mfma_f32_16x16x32_bf16(
                        af[mi], bfr[ni], acc[mi][ni], 0, 0, 0);
        }
        {
            bf16x8 af[4], bfr[4];
#pragma unroll
            for (int mi = 0; mi < 4; ++mi)
                af[mi] = *(const bf16x8*)&As1[(wr * 64 + mi * 16 + t16) * 32 + sw];
#pragma unroll
            for (int ni = 0; ni < 4; ++ni)
                bfr[ni] = *(const bf16x8*)&Bs1[(wc * 64 + ni * 16 + t16) * 32 + sw];
#pragma unroll
            for (int mi = 0; mi < 4; ++mi)
#pragma unroll
                for (int ni = 0; ni < 4; ++ni)
                    acc[mi][ni] = __builtin_amdgcn_mfma_f32_16x16x32_bf16(
                        af[mi], bfr[ni], acc[mi][ni], 0, 0, 0);
        }
        __syncthreads();
    }

    // C/D layout: col = lane&15, row = (lane>>4)*4 + reg
#pragma unroll
    for (int mi = 0; mi < 4; ++mi)
#pragma unroll
        for (int r = 0; r < 4; ++r) {
            size_t row = m0 + wr * 64 + mi * 16 + quad * 4 + r;
#pragma unroll
            for (int ni = 0; ni < 4; ++ni) {
                int col = (int)n0 + wc * 64 + ni * 16 + t16;
                if (col < CLASSES) C[row * (size_t)CLASSES + col] = acc[mi][ni][r];
            }
        }
}

// ---------------- launch -----------------------------------------------------
extern "C" void kernel_launch(void* const* d_in, const int* in_sizes, int n_in,
                              void* d_out, int out_size, void* d_ws, size_t ws_size,
                              hipStream_t stream) {
    const float* x   = (const float*)d_in[0];
    const float* w_d = (const float*)d_in[1];
    const float* w_l = (const float*)d_in[2];
    float* out = (float*)d_out;

    // workspace layout (173,015,040 B total, unchanged footprint):
    //   [0, 5.24MB)        B2t  (alive softmax..gemm2)
    //   region = +5.24MB:  xb (67.1MB) | wdT (10.5MB) | B2 (5.24MB)
    //   [+89.1MB, +173MB)  lp (83.9MB)  (written by gemm1_fused, read by gemm2)
    char* w = (char*)d_ws;
    u16* B2t = (u16*)w;
    char* region = w + 5242880;
    u16* xb  = (u16*)region;
    u16* wdT = (u16*)(region + 67108864);
    u16* B2  = (u16*)(region + 67108864 + 10485760);
    u16* lp  = (u16*)(region + 83886080);

    cast_x_k<<<32768, 256, 0, stream>>>((const float4*)x, (uint2*)xb);
    transpose_wd_k<<<dim3(64, 8, T_TREES), dim3(32, 8), 0, stream>>>(w_d, wdT);
    softmax_fold_k<<<640, 256, 0, stream>>>(w_l, B2);
    transpose_b2_k<<<dim3(80, 32), dim3(32, 8), 0, stream>>>(B2, B2t);
    // fused GEMM1 + sigmoid + leaf products -> lp  (dp + leafprod_k removed)
    gemm1_fused_k<<<dim3(128, T_TREES), 256, 0, stream>>>(xb, wdT, lp);
    // GEMM2: [16384,2560] x [1024,2560]^T -> out fp32 (cols < 1000)
    gemm2_k<<<dim3(128, 8), 256, 0, stream>>>(lp, B2t, out);
}

// Round 4
// 556.149 us; speedup vs baseline: 1.9955x; 1.9955x over previous
//
#include <hip/hip_runtime.h>
#include <stdint.h>

// ---------------- problem constants ----------------
#define T_TREES 10
#define IN_DIM  2048
#define BATCH   16384
#define CLASSES 1000
#define NDEC    255
#define NPAD    256          // decisions padded to 256
#define K2DIM   (T_TREES * NPAD)  // 2560
#define NPADC   1024         // classes padded to 1024

typedef unsigned short u16;
typedef float floatx4 __attribute__((ext_vector_type(4)));
typedef __bf16 bf16x8 __attribute__((ext_vector_type(8)));

// ---------------- helpers ----------------
__device__ __forceinline__ u16 f2bf(float f) {
    union { float f; uint32_t u; } v; v.f = f;
    uint32_t u = v.u;
    return (u16)((u + 0x7FFFu + ((u >> 16) & 1u)) >> 16);   // RNE
}
__device__ __forceinline__ float bf2f(u16 h) {
    union { uint32_t u; float f; } v; v.u = ((uint32_t)h) << 16;
    return v.f;
}

// async global->LDS, 16B per lane. LDS dest is wave-uniform base; HW writes
// lane i at base + i*16.
__device__ __forceinline__ void gld16(u16* lds, const u16* g) {
    __builtin_amdgcn_global_load_lds(
        (__attribute__((address_space(1))) const void*)g,
        (__attribute__((address_space(3))) void*)lds,
        16, 0, 0);
}

// ---------------- kernel 0: x fp32 -> bf16 ----------------
__global__ __launch_bounds__(256) void cast_x_k(const float4* __restrict__ x,
                                                uint2* __restrict__ xb) {
    int i = blockIdx.x * 256 + threadIdx.x;   // grid sized exactly
    float4 v = x[i];
    uint2 o;
    o.x = (uint32_t)f2bf(v.x) | ((uint32_t)f2bf(v.y) << 16);
    o.y = (uint32_t)f2bf(v.z) | ((uint32_t)f2bf(v.w) << 16);
    xb[i] = o;
}

// ---------------- kernel 1: w_d [t,i,255] fp32 -> wdT [t,256,2048] bf16 ----
__global__ void transpose_wd_k(const float* __restrict__ wd, u16* __restrict__ wdT) {
    __shared__ float tile[32][33];
    int tx = threadIdx.x, ty = threadIdx.y;
    int t = blockIdx.z;
    int i0 = blockIdx.x * 32, d0 = blockIdx.y * 32;
#pragma unroll
    for (int r = 0; r < 4; ++r) {
        int i = i0 + ty + r * 8;
        int d = d0 + tx;
        float v = (d < NDEC) ? wd[((size_t)t * IN_DIM + i) * NDEC + d] : 0.0f;
        tile[ty + r * 8][tx] = v;
    }
    __syncthreads();
#pragma unroll
    for (int r = 0; r < 4; ++r) {
        int dd = d0 + ty + r * 8;
        int ii = i0 + tx;
        wdT[((size_t)t * NPAD + dd) * IN_DIM + ii] = f2bf(tile[tx][ty + r * 8]);
    }
}

// ------- kernel 2: softmax(w_l) rows, fold leaf pairs, *0.1 -> B2 [2560,1024] bf16
__global__ __launch_bounds__(256) void softmax_fold_k(const float* __restrict__ wl,
                                                      u16* __restrict__ B2) {
    int wid = threadIdx.x >> 6, lane = threadIdx.x & 63;
    int idx = blockIdx.x * 4 + wid;          // 0..2559 = t*256 + m
    int t = idx >> 8, m = idx & 255;
    const float* r0 = wl + ((size_t)t * 512 + 2 * m) * CLASSES;
    const float* r1 = r0 + CLASSES;
    float v0[16], v1[16];
    float mx0 = -3.0e38f, mx1 = -3.0e38f;
#pragma unroll
    for (int j = 0; j < 16; ++j) {
        int c = lane + 64 * j;
        float a = (c < CLASSES) ? r0[c] : -3.0e38f;
        float b = (c < CLASSES) ? r1[c] : -3.0e38f;
        v0[j] = a; v1[j] = b;
        mx0 = fmaxf(mx0, a); mx1 = fmaxf(mx1, b);
    }
#pragma unroll
    for (int o = 32; o > 0; o >>= 1) {
        mx0 = fmaxf(mx0, __shfl_xor(mx0, o));
        mx1 = fmaxf(mx1, __shfl_xor(mx1, o));
    }
    float s0 = 0.f, s1 = 0.f;
#pragma unroll
    for (int j = 0; j < 16; ++j) {
        int c = lane + 64 * j;
        float e0 = (c < CLASSES) ? __expf(v0[j] - mx0) : 0.f;
        float e1 = (c < CLASSES) ? __expf(v1[j] - mx1) : 0.f;
        v0[j] = e0; v1[j] = e1; s0 += e0; s1 += e1;
    }
#pragma unroll
    for (int o = 32; o > 0; o >>= 1) { s0 += __shfl_xor(s0, o); s1 += __shfl_xor(s1, o); }
    float i0 = 0.1f / s0, i1 = 0.1f / s1;
#pragma unroll
    for (int j = 0; j < 16; ++j) {
        int c = lane + 64 * j;               // covers 0..1023 exactly
        float v = (c < CLASSES) ? (v0[j] * i0 + v1[j] * i1) : 0.f;
        B2[(size_t)idx * NPADC + c] = f2bf(v);
    }
}

// ---------------- kernel 3: B2 [2560,1024] -> B2t [1024,2560] bf16 ----------
__global__ void transpose_b2_k(const u16* __restrict__ B2, u16* __restrict__ B2t) {
    __shared__ u16 tile[32][33];
    int tx = threadIdx.x, ty = threadIdx.y;
    int k0 = blockIdx.x * 32, c0 = blockIdx.y * 32;
#pragma unroll
    for (int r = 0; r < 4; ++r)
        tile[ty + r * 8][tx] = B2[(size_t)(k0 + ty + r * 8) * NPADC + c0 + tx];
    __syncthreads();
#pragma unroll
    for (int r = 0; r < 4; ++r)
        B2t[(size_t)(c0 + ty + r * 8) * K2DIM + k0 + tx] = tile[tx][ty + r * 8];
}

// ---------------- GEMM1: C = A[M,K] @ B^T, 128x128 tile (round-2 winner) ----
// LDS tiles [128][32] bf16 with 16B-segment XOR swizzle (slot s^((r>>1)&3)):
// fragment ds_read_b128 is 2-way bank-aliased = free (m136). Staging fetches
// global segment (i&3)^((i>>3)&3) per lane (swizzle inverse, coalescing kept).
// Epilogue: sigmoid -> bf16 store (dp).
__global__ __launch_bounds__(256, 3) void gemm_bt(const u16* __restrict__ A,
                                                  const u16* __restrict__ B,
                                                  u16* __restrict__ Cout,
                                                  const int K, const long strideBz,
                                                  const long strideCz, const int ldc) {
    __shared__ __align__(16) u16 As[128 * 32];
    __shared__ __align__(16) u16 Bs[128 * 32];
    const int tid  = threadIdx.x;
    const int wid  = tid >> 6;
    const int lane = tid & 63;
    const int wr = wid >> 1, wc = wid & 1;
    const int quad = lane >> 4, t16 = lane & 15;

    const size_t m0 = (size_t)blockIdx.x * 128;
    const size_t n0 = (size_t)blockIdx.y * 128;
    const u16* Ag = A + m0 * (size_t)K;
    const u16* Bg = B + (size_t)blockIdx.z * strideBz + n0 * (size_t)K;

    const int ch0   = wid * 2;
    const int srow0 = ch0 * 16 + (lane >> 2);
    const int skk   = ((lane & 3) ^ ((lane >> 3) & 3)) * 8;
    const u16* ag0 = Ag + (size_t)srow0 * K + skk;
    const u16* ag1 = ag0 + (size_t)16 * K;
    const u16* bg0 = Bg + (size_t)srow0 * K + skk;
    const u16* bg1 = bg0 + (size_t)16 * K;
    u16* lA0 = &As[ch0 * 512];
    u16* lA1 = &As[ch0 * 512 + 512];
    u16* lB0 = &Bs[ch0 * 512];
    u16* lB1 = &Bs[ch0 * 512 + 512];
    const int sw = (quad ^ ((t16 >> 1) & 3)) * 8;

    floatx4 acc[4][4];
#pragma unroll
    for (int i = 0; i < 4; ++i)
#pragma unroll
        for (int j = 0; j < 4; ++j) acc[i][j] = (floatx4){0.f, 0.f, 0.f, 0.f};

    for (int k0 = 0; k0 < K; k0 += 32) {
        gld16(lA0, ag0 + k0);
        gld16(lA1, ag1 + k0);
        gld16(lB0, bg0 + k0);
        gld16(lB1, bg1 + k0);
        __syncthreads();   // drains vmcnt for the global_load_lds

        bf16x8 af[4], bfr[4];
#pragma unroll
        for (int mi = 0; mi < 4; ++mi)
            af[mi] = *(const bf16x8*)&As[(wr * 64 + mi * 16 + t16) * 32 + sw];
#pragma unroll
        for (int ni = 0; ni < 4; ++ni)
            bfr[ni] = *(const bf16x8*)&Bs[(wc * 64 + ni * 16 + t16) * 32 + sw];
#pragma unroll
        for (int mi = 0; mi < 4; ++mi)
#pragma unroll
            for (int ni = 0; ni < 4; ++ni)
                acc[mi][ni] = __builtin_amdgcn_mfma_f32_16x16x32_bf16(
                    af[mi], bfr[ni], acc[mi][ni], 0, 0, 0);
        __syncthreads();   // protect LDS before next stage
    }

    // C/D layout: col = lane&15, row = (lane>>4)*4 + reg
    u16* C = Cout + (size_t)blockIdx.z * strideCz;
#pragma unroll
    for (int mi = 0; mi < 4; ++mi)
#pragma unroll
        for (int r = 0; r < 4; ++r) {
            size_t row = m0 + wr * 64 + mi * 16 + quad * 4 + r;
#pragma unroll
            for (int ni = 0; ni < 4; ++ni) {
                int col = (int)n0 + wc * 64 + ni * 16 + t16;
                float v = acc[mi][ni][r];
                float p = 1.0f / (1.0f + __expf(-v));
                C[row * (size_t)ldc + col] = f2bf(p);
            }
        }
}

// ---------------- GEMM2: 256x128 tile, one-round grid ----------------------
// C[16384,1000] fp32 = lp[16384,2560] @ B2t[1024,2560]^T.
// BM=256: each wave owns 64 rows x 128 cols -> acc[4][8] (128 regs), 32 MFMA
// per barrier (half the vmcnt(0) drains per FLOP vs 128^2). Grid 64x8 = 512
// blocks; __launch_bounds__(256,2) caps regs at 256 (est ~210, no spill) ->
// 2 blocks/CU -> all 512 resident in ONE round (no tail quantization).
// LDS 24 KB. Same XOR swizzle -> 0 bank conflicts.
__global__ __launch_bounds__(256, 2) void gemm2_k(const u16* __restrict__ A,
                                                  const u16* __restrict__ B,
                                                  float* __restrict__ C) {
    __shared__ __align__(16) u16 As[256 * 32];
    __shared__ __align__(16) u16 Bs[128 * 32];
    const int tid  = threadIdx.x;
    const int wid  = tid >> 6;
    const int lane = tid & 63;
    const int quad = lane >> 4, t16 = lane & 15;

    const size_t m0 = (size_t)blockIdx.x * 256;
    const size_t n0 = (size_t)blockIdx.y * 128;
    const u16* Ag = A + m0 * (size_t)K2DIM;
    const u16* Bg = B + n0 * (size_t)K2DIM;

    // staging: A tile 256x32 = 16 chunks (wave w: chunks 4w..4w+3),
    //          B tile 128x32 = 8 chunks (wave w: chunks 2w..2w+1).
    // lane i -> row ch*16 + i/4, global segment (i&3)^((i>>3)&3).
    const int lrow = lane >> 2;
    const int skk  = ((lane & 3) ^ ((lane >> 3) & 3)) * 8;
    const u16* ag[4];
#pragma unroll
    for (int j = 0; j < 4; ++j)
        ag[j] = Ag + (size_t)((wid * 4 + j) * 16 + lrow) * K2DIM + skk;
    const u16* bg0 = Bg + (size_t)((wid * 2) * 16 + lrow) * K2DIM + skk;
    const u16* bg1 = bg0 + (size_t)16 * K2DIM;
    u16* lA = &As[wid * 4 * 512];
    u16* lB0 = &Bs[wid * 2 * 512];
    u16* lB1 = &Bs[wid * 2 * 512 + 512];
    const int sw = (quad ^ ((t16 >> 1) & 3)) * 8;

    floatx4 acc[4][8];
#pragma unroll
    for (int i = 0; i < 4; ++i)
#pragma unroll
        for (int j = 0; j < 8; ++j) acc[i][j] = (floatx4){0.f, 0.f, 0.f, 0.f};

    for (int k0 = 0; k0 < K2DIM; k0 += 32) {
#pragma unroll
        for (int j = 0; j < 4; ++j) gld16(lA + j * 512, ag[j] + k0);
        gld16(lB0, bg0 + k0);
        gld16(lB1, bg1 + k0);
        __syncthreads();

        bf16x8 af[4], bfr[8];
#pragma unroll
        for (int mi = 0; mi < 4; ++mi)
            af[mi] = *(const bf16x8*)&As[(wid * 64 + mi * 16 + t16) * 32 + sw];
#pragma unroll
        for (int ni = 0; ni < 8; ++ni)
            bfr[ni] = *(const bf16x8*)&Bs[(ni * 16 + t16) * 32 + sw];
#pragma unroll
        for (int mi = 0; mi < 4; ++mi)
#pragma unroll
            for (int ni = 0; ni < 8; ++ni)
                acc[mi][ni] = __builtin_amdgcn_mfma_f32_16x16x32_bf16(
                    af[mi], bfr[ni], acc[mi][ni], 0, 0, 0);
        __syncthreads();
    }

    // C/D layout: col = lane&15, row = (lane>>4)*4 + reg
#pragma unroll
    for (int mi = 0; mi < 4; ++mi)
#pragma unroll
        for (int r = 0; r < 4; ++r) {
            size_t row = m0 + wid * 64 + mi * 16 + quad * 4 + r;
#pragma unroll
            for (int ni = 0; ni < 8; ++ni) {
                int col = (int)n0 + ni * 16 + t16;
                if (col < CLASSES) C[row * (size_t)CLASSES + col] = acc[mi][ni][r];
            }
        }
}

// ---------------- kernel 5: leaf path products ------------------------------
// dp [t,b,256] bf16 decision probs -> lp [b, t*256+m] bf16 (m = folded leaf)
// factor(n,m): dec = (1<<n)-1 + (m>>(8-n)), side = (m>>(7-n))&1
__global__ __launch_bounds__(256) void leafprod_k(const u16* __restrict__ dp,
                                                  u16* __restrict__ lp) {
    __shared__ float P[4][256];
    int wid = threadIdx.x >> 6, lane = threadIdx.x & 63;
    int idx = blockIdx.x * 4 + wid;          // 0..163839 = t*16384 + b
    int t = idx >> 14, b = idx & 16383;
    const u16* row = dp + (size_t)idx * NPAD;
#pragma unroll
    for (int j = 0; j < 4; ++j)
        P[wid][lane + 64 * j] = bf2f(row[lane + 64 * j]);
    __syncthreads();
#pragma unroll
    for (int j = 0; j < 4; ++j) {
        int m = lane + 64 * j;
        float prod = 1.0f;
#pragma unroll
        for (int n = 0; n < 8; ++n) {
            int dec  = (1 << n) - 1 + (m >> (8 - n));
            int side = (m >> (7 - n)) & 1;
            float p  = P[wid][dec];
            prod *= side ? (1.0f - p) : p;
        }
        lp[(size_t)b * K2DIM + t * NPAD + m] = f2bf(prod);
    }
}

// ---------------- launch -----------------------------------------------------
extern "C" void kernel_launch(void* const* d_in, const int* in_sizes, int n_in,
                              void* d_out, int out_size, void* d_ws, size_t ws_size,
                              hipStream_t stream) {
    const float* x   = (const float*)d_in[0];
    const float* w_d = (const float*)d_in[1];
    const float* w_l = (const float*)d_in[2];
    float* out = (float*)d_out;

    // workspace layout (173,015,040 B total, with aliasing):
    //   [0, 5.24MB)        B2t  (alive softmax..gemm2)
    //   region = +5.24MB, 83.9MB:
    //       xb (67.1MB) | wdT (10.5MB) | B2 (5.24MB)   -- dead after gemm1
    //       lp (83.9MB) aliases the region, written after gemm1
    //   [+89.1MB, +173MB)  dp (83.9MB)
    char* w = (char*)d_ws;
    u16* B2t = (u16*)w;
    char* region = w + 5242880;
    u16* xb  = (u16*)region;
    u16* wdT = (u16*)(region + 67108864);
    u16* B2  = (u16*)(region + 67108864 + 10485760);
    u16* lp  = (u16*)region;
    u16* dp  = (u16*)(region + 83886080);

    cast_x_k<<<32768, 256, 0, stream>>>((const float4*)x, (uint2*)xb);
    transpose_wd_k<<<dim3(64, 8, T_TREES), dim3(32, 8), 0, stream>>>(w_d, wdT);
    softmax_fold_k<<<640, 256, 0, stream>>>(w_l, B2);
    transpose_b2_k<<<dim3(80, 32), dim3(32, 8), 0, stream>>>(B2, B2t);
    // GEMM1: [16384,2048] x [256,2048]^T per tree -> sigmoid -> dp bf16
    gemm_bt<<<dim3(128, 2, T_TREES), 256, 0, stream>>>(
        xb, wdT, dp, IN_DIM, (long)NPAD * IN_DIM, (long)BATCH * NPAD, NPAD);
    leafprod_k<<<40960, 256, 0, stream>>>(dp, lp);
    // GEMM2: [16384,2560] x [1024,2560]^T -> out fp32 (cols < 1000)
    gemm2_k<<<dim3(64, 8), 256, 0, stream>>>(lp, B2t, out);
}